// Round 2
// baseline (1117.496 us; speedup 1.0000x reference)
//
#include <hip/hip_runtime.h>
#include <hip/hip_bf16.h>

#define BSZ 2
#define TSEQ 2048
#define EMB 1024
#define NH 16
#define HD 64
#define SCALEF 0.125f
#define CLAMPV 50000.0f
#define NEG_BIG -1e30f

typedef __attribute__((ext_vector_type(8))) short short8;
typedef __attribute__((ext_vector_type(4))) short short4v;
typedef __attribute__((ext_vector_type(4))) float f32x4;

#define MFMA(a, b, c) __builtin_amdgcn_mfma_f32_16x16x32_bf16(a, b, c, 0, 0, 0)

__device__ __forceinline__ ushort f2bf(float f) {
  unsigned u = __builtin_bit_cast(unsigned, f);
  u += 0x7FFF + ((u >> 16) & 1);   // RTNE; all our values are finite
  return (ushort)(u >> 16);
}
__device__ __forceinline__ float bf2f(ushort h) {
  unsigned u = ((unsigned)h) << 16;
  return __builtin_bit_cast(float, u);
}

__device__ __forceinline__ void gl_lds16(const void* g, void* l) {
  __builtin_amdgcn_global_load_lds((const __attribute__((address_space(1))) unsigned*)g,
                                   (__attribute__((address_space(3))) unsigned*)l, 16, 0, 0);
}

// ---------------- f32 -> split bf16 (hi/lo) conversion, 7 arrays ----------------
struct CvtArgs {
  const float* src[7];
  ushort* dh[7];
  ushort* dl[7];
  int n4[7];
};

__global__ __launch_bounds__(256) void cvt_all(CvtArgs a) {
  const int y = blockIdx.y;
  const float* __restrict__ s = a.src[y];
  ushort* __restrict__ dh = a.dh[y];
  ushort* __restrict__ dl = a.dl[y];
  const int n4 = a.n4[y];
  const int stride = gridDim.x * 256;
  for (int i = blockIdx.x * 256 + threadIdx.x; i < n4; i += stride) {
    float4 v = ((const float4*)s)[i];
    float f0 = v.x, f1 = v.y, f2 = v.z, f3 = v.w;
    short4v oh, ol;
    ushort h;
    h = f2bf(f0); oh[0] = (short)h; ol[0] = (short)f2bf(f0 - bf2f(h));
    h = f2bf(f1); oh[1] = (short)h; ol[1] = (short)f2bf(f1 - bf2f(h));
    h = f2bf(f2); oh[2] = (short)h; ol[2] = (short)f2bf(f2 - bf2f(h));
    h = f2bf(f3); oh[3] = (short)h; ol[3] = (short)f2bf(f3 - bf2f(h));
    ((short4v*)dh)[i] = oh;
    ((short4v*)dl)[i] = ol;
  }
}

// ---------------- split-bf16 GEMM: C = (Ah+Al)[M,K] * (Bh+Bl)[N,K]^T (+bias) ----------------
// 3-term: Ah*Bh + Ah*Bl + Al*Bh  (drops ~2^-18 relative)
// MODE 0: split bf16 hi/lo natural output, val = (acc+bias)*scale
// MODE 1: split bf16 output transposed per-head for V: Vt[(b*NH+h)*HD+d][s]
// MODE 2: f32 natural output (+bias)
template<int MODE>
__global__ __launch_bounds__(256) void gemm_split(
    const ushort* __restrict__ Ah, const ushort* __restrict__ Al,
    const ushort* __restrict__ Bh, const ushort* __restrict__ Bl,
    const float* __restrict__ bias, void* __restrict__ C0, void* __restrict__ C1,
    int M, int N, int K, float scale)
{
  __shared__ ushort AsH[128 * 32];
  __shared__ ushort AsL[128 * 32];
  __shared__ ushort BsH[128 * 32];
  __shared__ ushort BsL[128 * 32];
  const int tid = threadIdx.x;
  const int lane = tid & 63;
  const int wid = tid >> 6;
  const int l15 = lane & 15, lhi = lane >> 4;
  const int wr = wid >> 1, wc = wid & 1;
  const int m0 = blockIdx.y * 128, n0 = blockIdx.x * 128;

  f32x4 acc[4][4] = {};

  // staging: 512 chunks of 16B per tile; phys chunk p at row r holds logical p ^ ((r>>1)&3)
  const int idx0 = tid, idx1 = tid + 256;
  const int ra0 = idx0 >> 2, ca0 = (idx0 & 3) ^ ((ra0 >> 1) & 3);
  const int ra1 = idx1 >> 2, ca1 = (idx1 & 3) ^ ((ra1 >> 1) & 3);
  const size_t aoff0 = (size_t)(m0 + ra0) * K + ca0 * 8;
  const size_t aoff1 = (size_t)(m0 + ra1) * K + ca1 * 8;
  const size_t boff0 = (size_t)(n0 + ra0) * K + ca0 * 8;
  const size_t boff1 = (size_t)(n0 + ra1) * K + ca1 * 8;

  for (int k0 = 0; k0 < K; k0 += 32) {
    gl_lds16(Ah + aoff0 + k0, AsH + idx0 * 8);
    gl_lds16(Ah + aoff1 + k0, AsH + idx1 * 8);
    gl_lds16(Al + aoff0 + k0, AsL + idx0 * 8);
    gl_lds16(Al + aoff1 + k0, AsL + idx1 * 8);
    gl_lds16(Bh + boff0 + k0, BsH + idx0 * 8);
    gl_lds16(Bh + boff1 + k0, BsH + idx1 * 8);
    gl_lds16(Bl + boff0 + k0, BsL + idx0 * 8);
    gl_lds16(Bl + boff1 + k0, BsL + idx1 * 8);
    __syncthreads();

    short8 ah8[4], al8[4], bh8[4], bl8[4];
#pragma unroll
    for (int mi = 0; mi < 4; mi++) {
      int r = wr * 64 + mi * 16 + l15;
      int off = r * 32 + ((lhi ^ ((r >> 1) & 3)) * 8);
      ah8[mi] = *(const short8*)(AsH + off);
      al8[mi] = *(const short8*)(AsL + off);
    }
#pragma unroll
    for (int ni = 0; ni < 4; ni++) {
      int r = wc * 64 + ni * 16 + l15;
      int off = r * 32 + ((lhi ^ ((r >> 1) & 3)) * 8);
      bh8[ni] = *(const short8*)(BsH + off);
      bl8[ni] = *(const short8*)(BsL + off);
    }
#pragma unroll
    for (int mi = 0; mi < 4; mi++)
#pragma unroll
      for (int ni = 0; ni < 4; ni++) {
        acc[mi][ni] = MFMA(ah8[mi], bh8[ni], acc[mi][ni]);
        acc[mi][ni] = MFMA(ah8[mi], bl8[ni], acc[mi][ni]);
        acc[mi][ni] = MFMA(al8[mi], bh8[ni], acc[mi][ni]);
      }
    __syncthreads();
  }

  // epilogue — C/D layout: col = lane&15, row = (lane>>4)*4 + reg
#pragma unroll
  for (int mi = 0; mi < 4; mi++) {
#pragma unroll
    for (int ni = 0; ni < 4; ni++) {
      const int col = n0 + wc * 64 + ni * 16 + l15;
      const float bv = bias[col];
      const int rowb = m0 + wr * 64 + mi * 16 + lhi * 4;
      if (MODE == 0) {
        ushort* Chp = (ushort*)C0;
        ushort* Clp = (ushort*)C1;
#pragma unroll
        for (int r = 0; r < 4; r++) {
          float val = (acc[mi][ni][r] + bv) * scale;
          ushort hh = f2bf(val);
          Chp[(size_t)(rowb + r) * N + col] = hh;
          Clp[(size_t)(rowb + r) * N + col] = f2bf(val - bf2f(hh));
        }
      } else if (MODE == 1) {
        const int bb = rowb >> 11, s = rowb & (TSEQ - 1);
        short4v oh, ol;
#pragma unroll
        for (int r = 0; r < 4; r++) {
          float val = acc[mi][ni][r] + bv;
          ushort hh = f2bf(val);
          oh[r] = (short)hh;
          ol[r] = (short)f2bf(val - bf2f(hh));
        }
        size_t base = ((size_t)((bb * NH + (col >> 6)) * HD + (col & 63))) * TSEQ + s;
        *(short4v*)((ushort*)C0 + base) = oh;
        *(short4v*)((ushort*)C1 + base) = ol;
      } else {
        float* Cp = (float*)C0;
#pragma unroll
        for (int r = 0; r < 4; r++)
          Cp[(size_t)(rowb + r) * N + col] = acc[mi][ni][r] + bv;
      }
    }
  }
}

// ---------------- fused attention, split-bf16 ----------------
// Grid (TSEQ/64, NH, BSZ), 256 threads (4 waves). Wave w owns q-rows [16w,16w+16).
// Sweep 1: online (m,l).  Sweep 2: recompute identical scores, write normalized
// f32 weights, split-stage weights into LDS, 3-term PV.
__global__ __launch_bounds__(256) void attn_kernel(
    const ushort* __restrict__ Qh, const ushort* __restrict__ Ql,   // [4096,1024] pre-scaled
    const ushort* __restrict__ Kh, const ushort* __restrict__ Kl,   // [4096,1024]
    const ushort* __restrict__ Vh, const ushort* __restrict__ Vl,   // [(b*NH+h)*HD+d][2048]
    const int* __restrict__ maskg,                                  // [2,2048]
    float* __restrict__ Wout,                                       // [2,16,2048,2048] f32
    ushort* __restrict__ Ch, ushort* __restrict__ Cl)               // ctx hi/lo [4096,1024]
{
  const int tq = blockIdx.x, h = blockIdx.y, b = blockIdx.z;
  const int tid = threadIdx.x;
  const int lane = tid & 63, wid = tid >> 6;
  const int l15 = lane & 15, lhi = lane >> 4;
  const int bh = b * NH + h;
  const int q0 = b * TSEQ + tq * 64;

  // 8 x 8KB = 64KB -> 2 blocks/CU. Rows are 64 ushorts = 8 chunks of 16B;
  // phys chunk p at row r holds logical p ^ (r&7)  (2-way conflict = free).
  __shared__ ushort QsH[64 * 64], QsL[64 * 64];
  __shared__ ushort KsH[64 * 64], KsL[64 * 64];
  __shared__ ushort VsH[64 * 64], VsL[64 * 64];
  __shared__ ushort WsH[64 * 64], WsL[64 * 64];

  // stage Q tile once (lane-linear LDS dest, pre-swizzled global src)
#pragma unroll
  for (int t = 0; t < 2; t++) {
    int idx = t * 256 + tid, r = idx >> 3, c = (idx & 7) ^ (r & 7);
    const size_t go = (size_t)(q0 + r) * EMB + h * HD + c * 8;
    gl_lds16(Qh + go, QsH + idx * 8);
    gl_lds16(Ql + go, QsL + idx * 8);
  }

  float mrow[4], lrow[4];
#pragma unroll
  for (int i = 0; i < 4; i++) { mrow[i] = NEG_BIG; lrow[i] = 0.f; }

  // ---------------- sweep 1: running (m, l) ----------------
  for (int s0 = 0; s0 < TSEQ; s0 += 64) {
    __syncthreads();
#pragma unroll
    for (int t = 0; t < 2; t++) {
      int idx = t * 256 + tid, r = idx >> 3, c = (idx & 7) ^ (r & 7);
      const size_t go = (size_t)(b * TSEQ + s0 + r) * EMB + h * HD + c * 8;
      gl_lds16(Kh + go, KsH + idx * 8);
      gl_lds16(Kl + go, KsL + idx * 8);
    }
    __syncthreads();

    f32x4 acc[4] = {};
#pragma unroll
    for (int ks = 0; ks < 2; ks++) {
      const int ar = wid * 16 + l15;
      const int aoff = ar * 64 + (((ks * 4 + lhi) ^ (ar & 7)) * 8);
      short8 aH = *(const short8*)(QsH + aoff);
      short8 aL = *(const short8*)(QsL + aoff);
#pragma unroll
      for (int ni = 0; ni < 4; ni++) {
        const int br = ni * 16 + l15;
        const int boff = br * 64 + (((ks * 4 + lhi) ^ (br & 7)) * 8);
        short8 bH = *(const short8*)(KsH + boff);
        short8 bL = *(const short8*)(KsL + boff);
        acc[ni] = MFMA(aH, bH, acc[ni]);
        acc[ni] = MFMA(aH, bL, acc[ni]);
        acc[ni] = MFMA(aL, bH, acc[ni]);
      }
    }

    int msk[4];
#pragma unroll
    for (int ni = 0; ni < 4; ni++)
      msk[ni] = maskg[b * TSEQ + s0 + ni * 16 + l15];

#pragma unroll
    for (int r = 0; r < 4; r++) {
      float vals[4];
      float tm = NEG_BIG;
#pragma unroll
      for (int ni = 0; ni < 4; ni++) {
        float vv = fminf(fmaxf(acc[ni][r], -CLAMPV), CLAMPV);
        vv = msk[ni] ? vv : NEG_BIG;
        vals[ni] = vv;
        tm = fmaxf(tm, vv);
      }
#pragma unroll
      for (int d = 1; d < 16; d <<= 1) tm = fmaxf(tm, __shfl_xor(tm, d));
      float mnew = fmaxf(mrow[r], tm);
      float se = 0.f;
#pragma unroll
      for (int ni = 0; ni < 4; ni++) se += __expf(vals[ni] - mnew);
#pragma unroll
      for (int d = 1; d < 16; d <<= 1) se += __shfl_xor(se, d);
      lrow[r] = lrow[r] * __expf(mrow[r] - mnew) + se;
      mrow[r] = mnew;
    }
  }

  float invl[4];
#pragma unroll
  for (int i = 0; i < 4; i++) invl[i] = 1.0f / lrow[i];

  f32x4 apv[4] = {};

  // ---------------- sweep 2: weights out + PV ----------------
  for (int s0 = 0; s0 < TSEQ; s0 += 64) {
    __syncthreads();
#pragma unroll
    for (int t = 0; t < 2; t++) {
      int idx = t * 256 + tid, r = idx >> 3, c = (idx & 7) ^ (r & 7);
      const size_t go = (size_t)(b * TSEQ + s0 + r) * EMB + h * HD + c * 8;
      gl_lds16(Kh + go, KsH + idx * 8);
      gl_lds16(Kl + go, KsL + idx * 8);
      const size_t gv = (size_t)(bh * HD + r) * TSEQ + s0 + c * 8;
      gl_lds16(Vh + gv, VsH + idx * 8);
      gl_lds16(Vl + gv, VsL + idx * 8);
    }
    __syncthreads();

    // identical score recompute (bit-exact vs sweep 1)
    f32x4 acc[4] = {};
#pragma unroll
    for (int ks = 0; ks < 2; ks++) {
      const int ar = wid * 16 + l15;
      const int aoff = ar * 64 + (((ks * 4 + lhi) ^ (ar & 7)) * 8);
      short8 aH = *(const short8*)(QsH + aoff);
      short8 aL = *(const short8*)(QsL + aoff);
#pragma unroll
      for (int ni = 0; ni < 4; ni++) {
        const int br = ni * 16 + l15;
        const int boff = br * 64 + (((ks * 4 + lhi) ^ (br & 7)) * 8);
        short8 bH = *(const short8*)(KsH + boff);
        short8 bL = *(const short8*)(KsL + boff);
        acc[ni] = MFMA(aH, bH, acc[ni]);
        acc[ni] = MFMA(aH, bL, acc[ni]);
        acc[ni] = MFMA(aL, bH, acc[ni]);
      }
    }

    int msk[4];
#pragma unroll
    for (int ni = 0; ni < 4; ni++)
      msk[ni] = maskg[b * TSEQ + s0 + ni * 16 + l15];

#pragma unroll
    for (int r = 0; r < 4; r++) {
      const int rowl = wid * 16 + lhi * 4 + r;
#pragma unroll
      for (int ni = 0; ni < 4; ni++) {
        const int col = ni * 16 + l15;
        float vv = fminf(fmaxf(acc[ni][r], -CLAMPV), CLAMPV);
        float w = msk[ni] ? __expf(vv - mrow[r]) * invl[r] : 0.0f;
        Wout[(size_t)(bh * TSEQ + tq * 64 + rowl) * TSEQ + s0 + col] = w;
        ushort wh = f2bf(w);
        const int p = rowl * 64 + (((col >> 3) ^ (rowl & 7)) * 8) + (col & 7);
        WsH[p] = wh;
        WsL[p] = f2bf(w - bf2f(wh));
      }
    }

    // PV (Ws rows are wave-private; same-wave LDS ordering handled by lgkmcnt)
#pragma unroll
    for (int ks = 0; ks < 2; ks++) {
      const int ar = wid * 16 + l15;
      const int aoff = ar * 64 + (((ks * 4 + lhi) ^ (ar & 7)) * 8);
      short8 wH = *(const short8*)(WsH + aoff);
      short8 wL = *(const short8*)(WsL + aoff);
#pragma unroll
      for (int ni = 0; ni < 4; ni++) {
        const int dr = ni * 16 + l15;
        const int voff = dr * 64 + (((ks * 4 + lhi) ^ (dr & 7)) * 8);
        short8 vH = *(const short8*)(VsH + voff);
        short8 vL = *(const short8*)(VsL + voff);
        apv[ni] = MFMA(wH, vH, apv[ni]);
        apv[ni] = MFMA(wH, vL, apv[ni]);
        apv[ni] = MFMA(wL, vH, apv[ni]);
      }
    }
  }

  // ctx epilogue: split hi/lo
#pragma unroll
  for (int ni = 0; ni < 4; ni++) {
#pragma unroll
    for (int r = 0; r < 4; r++) {
      const int rowl = wid * 16 + lhi * 4 + r;
      const int d = ni * 16 + l15;
      float c = apv[ni][r];
      ushort hh = f2bf(c);
      const size_t go = (size_t)(q0 + rowl) * EMB + h * HD + d;
      Ch[go] = hh;
      Cl[go] = f2bf(c - bf2f(hh));
    }
  }
}

// ---------------- launch ----------------
extern "C" void kernel_launch(void* const* d_in, const int* in_sizes, int n_in,
                              void* d_out, int out_size, void* d_ws, size_t ws_size,
                              hipStream_t stream) {
  (void)in_sizes; (void)n_in; (void)out_size; (void)ws_size;
  const float* q   = (const float*)d_in[0];
  const float* k   = (const float*)d_in[1];
  const float* v   = (const float*)d_in[2];
  const int*  mask = (const int*)d_in[3];
  const float* Wq  = (const float*)d_in[4];
  const float* bq  = (const float*)d_in[5];
  const float* Wk  = (const float*)d_in[6];
  const float* bk  = (const float*)d_in[7];
  const float* Wv  = (const float*)d_in[8];
  const float* bv  = (const float*)d_in[9];
  const float* Wo  = (const float*)d_in[10];
  const float* bo  = (const float*)d_in[11];

  const size_t TE = (size_t)BSZ * TSEQ * EMB;   // 4M elements
  const size_t WE = (size_t)EMB * EMB;          // 1M elements

  ushort* ws  = (ushort*)d_ws;
  ushort* qbh = ws;        ushort* qbl = qbh + TE;
  ushort* kbh = qbl + TE;  ushort* kbl = kbh + TE;
  ushort* vbh = kbl + TE;  ushort* vbl = vbh + TE;
  ushort* wqh = vbl + TE;  ushort* wql = wqh + WE;
  ushort* wkh = wql + WE;  ushort* wkl = wkh + WE;
  ushort* wvh = wkl + WE;  ushort* wvl = wvh + WE;
  ushort* woh = wvl + WE;  ushort* wol = woh + WE;
  ushort* Qph = wol + WE;  ushort* Qpl = Qph + TE;
  ushort* Kph = Qpl + TE;  ushort* Kpl = Kph + TE;
  ushort* Vth = Kpl + TE;  ushort* Vtl = Vth + TE;
  // ctx aliases q's staging buffers (q no longer needed after Qp GEMM)
  ushort* Cth = qbh;       ushort* Ctl = qbl;

  CvtArgs ca;
  ca.src[0] = q;  ca.dh[0] = qbh; ca.dl[0] = qbl; ca.n4[0] = (int)(TE / 4);
  ca.src[1] = k;  ca.dh[1] = kbh; ca.dl[1] = kbl; ca.n4[1] = (int)(TE / 4);
  ca.src[2] = v;  ca.dh[2] = vbh; ca.dl[2] = vbl; ca.n4[2] = (int)(TE / 4);
  ca.src[3] = Wq; ca.dh[3] = wqh; ca.dl[3] = wql; ca.n4[3] = (int)(WE / 4);
  ca.src[4] = Wk; ca.dh[4] = wkh; ca.dl[4] = wkl; ca.n4[4] = (int)(WE / 4);
  ca.src[5] = Wv; ca.dh[5] = wvh; ca.dl[5] = wvl; ca.n4[5] = (int)(WE / 4);
  ca.src[6] = Wo; ca.dh[6] = woh; ca.dl[6] = wol; ca.n4[6] = (int)(WE / 4);
  cvt_all<<<dim3(512, 7), 256, 0, stream>>>(ca);

  dim3 gproj(EMB / 128, (BSZ * TSEQ) / 128);   // (8, 32)
  gemm_split<0><<<gproj, 256, 0, stream>>>(qbh, qbl, wqh, wql, bq, Qph, Qpl,
                                           BSZ * TSEQ, EMB, EMB, SCALEF);
  gemm_split<0><<<gproj, 256, 0, stream>>>(kbh, kbl, wkh, wkl, bk, Kph, Kpl,
                                           BSZ * TSEQ, EMB, EMB, 1.0f);
  gemm_split<1><<<gproj, 256, 0, stream>>>(vbh, vbl, wvh, wvl, bv, Vth, Vtl,
                                           BSZ * TSEQ, EMB, EMB, 1.0f);

  float* outp = (float*)d_out;
  float* wout = outp + TE;   // outputs concat: out [2,2048,1024] then weights [2,16,2048,2048]
  attn_kernel<<<dim3(TSEQ / 64, NH, BSZ), 256, 0, stream>>>(
      Qph, Qpl, Kph, Kpl, Vth, Vtl, mask, wout, Cth, Ctl);

  gemm_split<2><<<gproj, 256, 0, stream>>>(Cth, Ctl, woh, wol, bo, outp, nullptr,
                                           BSZ * TSEQ, EMB, EMB, 1.0f);
}

// Round 3
// 880.829 us; speedup vs baseline: 1.2687x; 1.2687x over previous
//
#include <hip/hip_runtime.h>
#include <hip/hip_bf16.h>

#define BSZ 2
#define TSEQ 2048
#define EMB 1024
#define NH 16
#define HD 64
#define SCALEF 0.125f
#define CLAMPV 50000.0f
#define NEG_BIG -1e30f

typedef __attribute__((ext_vector_type(8))) short short8;
typedef __attribute__((ext_vector_type(4))) short short4v;
typedef __attribute__((ext_vector_type(4))) float f32x4;

#define MFMA(a, b, c) __builtin_amdgcn_mfma_f32_16x16x32_bf16(a, b, c, 0, 0, 0)

__device__ __forceinline__ ushort f2bf(float f) {
  unsigned u = __builtin_bit_cast(unsigned, f);
  u += 0x7FFF + ((u >> 16) & 1);   // RTNE; all values finite
  return (ushort)(u >> 16);
}
__device__ __forceinline__ float bf2f(ushort h) {
  unsigned u = ((unsigned)h) << 16;
  return __builtin_bit_cast(float, u);
}

__device__ __forceinline__ void gl_lds16(const void* g, void* l) {
  __builtin_amdgcn_global_load_lds((const __attribute__((address_space(1))) unsigned*)g,
                                   (__attribute__((address_space(3))) unsigned*)l, 16, 0, 0);
}

// ---------------- mask -> 64-bit ballots per 64-col tile ----------------
__global__ __launch_bounds__(256) void mask_bits(const int* __restrict__ m,
                                                 unsigned long long* __restrict__ mb) {
  const int gw = (blockIdx.x * 256 + threadIdx.x) >> 6;   // 0..63
  const int lane = threadIdx.x & 63;
  const int b = gw >> 5, t = gw & 31;
  unsigned long long bits = __ballot(m[b * TSEQ + t * 64 + lane] != 0);
  if (lane == 0) mb[gw] = bits;
}

// ---------------- f32 -> split bf16 (hi/lo), 7 arrays ----------------
struct CvtArgs {
  const float* src[7];
  ushort* dh[7];
  ushort* dl[7];
  int n4[7];
};

__global__ __launch_bounds__(256) void cvt_all(CvtArgs a) {
  const int y = blockIdx.y;
  const float* __restrict__ s = a.src[y];
  ushort* __restrict__ dh = a.dh[y];
  ushort* __restrict__ dl = a.dl[y];
  const int n4 = a.n4[y];
  const int stride = gridDim.x * 256;
  for (int i = blockIdx.x * 256 + threadIdx.x; i < n4; i += stride) {
    float4 v = ((const float4*)s)[i];
    short4v oh, ol;
    ushort h;
    h = f2bf(v.x); oh[0] = (short)h; ol[0] = (short)f2bf(v.x - bf2f(h));
    h = f2bf(v.y); oh[1] = (short)h; ol[1] = (short)f2bf(v.y - bf2f(h));
    h = f2bf(v.z); oh[2] = (short)h; ol[2] = (short)f2bf(v.z - bf2f(h));
    h = f2bf(v.w); oh[3] = (short)h; ol[3] = (short)f2bf(v.w - bf2f(h));
    ((short4v*)dh)[i] = oh;
    ((short4v*)dl)[i] = ol;
  }
}

// ---------------- split-bf16 GEMM, 128x64 tile, BK=32, double-buffered ----------------
// C = (Ah+Al)[M,K] * (Bh+Bl)[N,K]^T (+bias); 3-term Ah*Bh + Ah*Bl + Al*Bh.
// MODE 0: split hi/lo bf16 natural output, val=(acc+bias)*scale
// MODE 1: bf16 HI-only output transposed per-head (V): Vt[(b*NH+h)*HD+d][s]
// MODE 2: f32 natural output (+bias)
template<int MODE>
__global__ __launch_bounds__(256, 2) void gemm_split(
    const ushort* __restrict__ Ah, const ushort* __restrict__ Al,
    const ushort* __restrict__ Bh, const ushort* __restrict__ Bl,
    const float* __restrict__ bias, void* __restrict__ C0, void* __restrict__ C1,
    int M, int N, int K, float scale)
{
  __shared__ ushort AsH[2][128 * 32];
  __shared__ ushort AsL[2][128 * 32];
  __shared__ ushort BsH[2][64 * 32];
  __shared__ ushort BsL[2][64 * 32];
  const int tid = threadIdx.x;
  const int lane = tid & 63, wid = tid >> 6;
  const int l15 = lane & 15, lhi = lane >> 4;
  const int wr = wid >> 1, wc = wid & 1;
  const int m0 = blockIdx.y * 128, n0 = blockIdx.x * 64;

  f32x4 acc[4][2] = {};

  // A: 512 16B-chunks/tile (rows of 4 chunks); phys chunk p at row r holds logical p^((r>>1)&3)
  const int ra0 = tid >> 2,         ca0 = (tid & 3) ^ ((ra0 >> 1) & 3);
  const int ra1 = (tid + 256) >> 2, ca1 = (tid & 3) ^ ((ra1 >> 1) & 3);
  const size_t ga0 = (size_t)(m0 + ra0) * K + ca0 * 8;
  const size_t ga1 = (size_t)(m0 + ra1) * K + ca1 * 8;
  // B: 256 chunks
  const int rb = tid >> 2, cb = (tid & 3) ^ ((rb >> 1) & 3);
  const size_t gb = (size_t)(n0 + rb) * K + cb * 8;

  const int NT = K >> 5;
  gl_lds16(Ah + ga0, &AsH[0][tid * 8]);
  gl_lds16(Ah + ga1, &AsH[0][(tid + 256) * 8]);
  gl_lds16(Al + ga0, &AsL[0][tid * 8]);
  gl_lds16(Al + ga1, &AsL[0][(tid + 256) * 8]);
  gl_lds16(Bh + gb,  &BsH[0][tid * 8]);
  gl_lds16(Bl + gb,  &BsL[0][tid * 8]);
  __syncthreads();

  for (int t = 0; t < NT; ++t) {
    const int cur = t & 1;
    if (t + 1 < NT) {               // prefetch next tile into other buffer
      const int nx = cur ^ 1;
      const size_t ko = (size_t)(t + 1) * 32;
      gl_lds16(Ah + ga0 + ko, &AsH[nx][tid * 8]);
      gl_lds16(Ah + ga1 + ko, &AsH[nx][(tid + 256) * 8]);
      gl_lds16(Al + ga0 + ko, &AsL[nx][tid * 8]);
      gl_lds16(Al + ga1 + ko, &AsL[nx][(tid + 256) * 8]);
      gl_lds16(Bh + gb + ko,  &BsH[nx][tid * 8]);
      gl_lds16(Bl + gb + ko,  &BsL[nx][tid * 8]);
    }
    short8 ah8[4], al8[4], bh8[2], bl8[2];
#pragma unroll
    for (int mi = 0; mi < 4; mi++) {
      int r = wr * 64 + mi * 16 + l15;
      int off = r * 32 + ((lhi ^ ((r >> 1) & 3)) * 8);
      ah8[mi] = *(const short8*)(&AsH[cur][off]);
      al8[mi] = *(const short8*)(&AsL[cur][off]);
    }
#pragma unroll
    for (int ni = 0; ni < 2; ni++) {
      int c = wc * 32 + ni * 16 + l15;
      int off = c * 32 + ((lhi ^ ((c >> 1) & 3)) * 8);
      bh8[ni] = *(const short8*)(&BsH[cur][off]);
      bl8[ni] = *(const short8*)(&BsL[cur][off]);
    }
#pragma unroll
    for (int mi = 0; mi < 4; mi++)
#pragma unroll
      for (int ni = 0; ni < 2; ni++) {
        acc[mi][ni] = MFMA(ah8[mi], bh8[ni], acc[mi][ni]);
        acc[mi][ni] = MFMA(ah8[mi], bl8[ni], acc[mi][ni]);
        acc[mi][ni] = MFMA(al8[mi], bh8[ni], acc[mi][ni]);
      }
    __syncthreads();
  }

  // epilogue — C/D layout: col = lane&15, row = (lane>>4)*4 + reg
  if (MODE == 0) {
    ushort* Chp = (ushort*)C0;
    ushort* Clp = (ushort*)C1;
#pragma unroll
    for (int mi = 0; mi < 4; mi++)
#pragma unroll
      for (int ni = 0; ni < 2; ni++) {
        const int col = n0 + wc * 32 + ni * 16 + l15;
        const float bv = bias[col];
        const int rowb = m0 + wr * 64 + mi * 16 + lhi * 4;
#pragma unroll
        for (int r = 0; r < 4; r++) {
          float val = (acc[mi][ni][r] + bv) * scale;
          ushort hh = f2bf(val);
          Chp[(size_t)(rowb + r) * N + col] = hh;
          Clp[(size_t)(rowb + r) * N + col] = f2bf(val - bf2f(hh));
        }
      }
  } else if (MODE == 2) {
    float* Cp = (float*)C0;
#pragma unroll
    for (int mi = 0; mi < 4; mi++)
#pragma unroll
      for (int ni = 0; ni < 2; ni++) {
        const int col = n0 + wc * 32 + ni * 16 + l15;
        const float bv = bias[col];
        const int rowb = m0 + wr * 64 + mi * 16 + lhi * 4;
#pragma unroll
        for (int r = 0; r < 4; r++)
          Cp[(size_t)(rowb + r) * N + col] = acc[mi][ni][r] + bv;
      }
  } else {
    // MODE 1: transpose in LDS (reuse AsH = 16KB), then coalesced 16B stores.
    ushort* WtH = &AsH[0][0];   // [64 d][128 s], phys s = s ^ ((d&7)<<3)
#pragma unroll
    for (int mi = 0; mi < 4; mi++)
#pragma unroll
      for (int ni = 0; ni < 2; ni++) {
        const int d = wc * 32 + ni * 16 + l15;
        const float bv = bias[n0 + d];
        const int s = wr * 64 + mi * 16 + lhi * 4;
#pragma unroll
        for (int r = 0; r < 4; r++)
          WtH[d * 128 + ((s + r) ^ ((d & 7) << 3))] = f2bf(acc[mi][ni][r] + bv);
      }
    __syncthreads();
    const int bb = m0 >> 11, head = n0 >> 6;
    ushort* Vt = (ushort*)C0;
#pragma unroll
    for (int it = 0; it < 4; it++) {
      int idx = it * 256 + tid;
      int d = idx >> 4, c = idx & 15;
      short8 hv = *(const short8*)(WtH + d * 128 + ((c * 8) ^ ((d & 7) << 3)));
      *(short8*)(Vt + (size_t)((bb * NH + head) * HD + d) * TSEQ + (m0 & (TSEQ - 1)) + c * 8) = hv;
    }
  }
}

// ---------------- fused attention ----------------
// Grid (TSEQ/64, NH, BSZ), 256 threads (4 waves), 32KB LDS -> 4 blocks/CU.
// Q fragments hoisted to registers; sweep 1 = online (m,l); sweep 2 recomputes
// identical scores, writes normalized f32 weights (nontemporal), PV single-term.
__global__ __launch_bounds__(256, 4) void attn_kernel(
    const ushort* __restrict__ Qh, const ushort* __restrict__ Ql,   // pre-scaled
    const ushort* __restrict__ Kh, const ushort* __restrict__ Kl,
    const ushort* __restrict__ Vt,                                  // [(b*NH+h)*HD+d][2048]
    const unsigned long long* __restrict__ mbits,                   // [2][32]
    float* __restrict__ Wout,                                       // [2,16,2048,2048]
    ushort* __restrict__ Ch, ushort* __restrict__ Cl)               // ctx hi/lo
{
  const int tq = blockIdx.x, h = blockIdx.y, b = blockIdx.z;
  const int tid = threadIdx.x;
  const int lane = tid & 63, wid = tid >> 6;
  const int l15 = lane & 15, lhi = lane >> 4;
  const int bh = b * NH + h;
  const int q0 = b * TSEQ + tq * 64;

  // rows of 64 ushorts = 8 chunks of 16B; phys chunk p at row r holds logical p^(r&7)
  __shared__ ushort bufA[64 * 64], bufB[64 * 64], VsH[64 * 64], WsH[64 * 64];

  // per-tile staging geometry (lane-linear LDS dest, pre-swizzled global src)
  const int r0 = tid >> 3,          c0 = (tid & 7) ^ (r0 & 7);
  const int r1 = (tid + 256) >> 3,  c1 = (tid & 7) ^ (r1 & 7);

  // ---- stage Q, hoist fragments to registers ----
  {
    const size_t g0 = (size_t)(q0 + r0) * EMB + h * HD + c0 * 8;
    const size_t g1 = (size_t)(q0 + r1) * EMB + h * HD + c1 * 8;
    gl_lds16(Qh + g0, bufA + tid * 8);
    gl_lds16(Qh + g1, bufA + (tid + 256) * 8);
    gl_lds16(Ql + g0, bufB + tid * 8);
    gl_lds16(Ql + g1, bufB + (tid + 256) * 8);
  }
  __syncthreads();
  short8 qH[2], qL[2];
  {
    const int ar = wid * 16 + l15;
#pragma unroll
    for (int ks = 0; ks < 2; ks++) {
      const int off = ar * 64 + (((ks * 4 + lhi) ^ (ar & 7)) * 8);
      qH[ks] = *(const short8*)(bufA + off);
      qL[ks] = *(const short8*)(bufB + off);
    }
  }
  __syncthreads();   // all waves done reading Q before K overwrites bufA/bufB

  const size_t kg0 = (size_t)(b * TSEQ + r0) * EMB + h * HD + c0 * 8;
  const size_t kg1 = (size_t)(b * TSEQ + r1) * EMB + h * HD + c1 * 8;
  const size_t vg0 = (size_t)(bh * HD + r0) * TSEQ + c0 * 8;
  const size_t vg1 = (size_t)(bh * HD + r1) * TSEQ + c1 * 8;

  float mrow[4], lrow[4];
#pragma unroll
  for (int i = 0; i < 4; i++) { mrow[i] = NEG_BIG; lrow[i] = 0.f; }

  // ---------------- sweep 1: running (m, l) ----------------
  for (int s0 = 0; s0 < TSEQ; s0 += 64) {
    gl_lds16(Kh + kg0 + (size_t)s0 * EMB, bufA + tid * 8);
    gl_lds16(Kh + kg1 + (size_t)s0 * EMB, bufA + (tid + 256) * 8);
    gl_lds16(Kl + kg0 + (size_t)s0 * EMB, bufB + tid * 8);
    gl_lds16(Kl + kg1 + (size_t)s0 * EMB, bufB + (tid + 256) * 8);
    __syncthreads();

    f32x4 acc[4] = {};
#pragma unroll
    for (int ks = 0; ks < 2; ks++) {
#pragma unroll
      for (int ni = 0; ni < 4; ni++) {
        const int br = ni * 16 + l15;
        const int boff = br * 64 + (((ks * 4 + lhi) ^ (br & 7)) * 8);
        short8 bH = *(const short8*)(bufA + boff);
        short8 bL = *(const short8*)(bufB + boff);
        acc[ni] = MFMA(qH[ks], bH, acc[ni]);
        acc[ni] = MFMA(qH[ks], bL, acc[ni]);
        acc[ni] = MFMA(qL[ks], bH, acc[ni]);
      }
    }

    const unsigned long long mb = mbits[b * 32 + (s0 >> 6)];
    float fm[4];
#pragma unroll
    for (int ni = 0; ni < 4; ni++)
      fm[ni] = ((mb >> (ni * 16 + l15)) & 1ull) ? 0.f : NEG_BIG;

#pragma unroll
    for (int r = 0; r < 4; r++) {
      float vals[4];
      float tm = NEG_BIG;
#pragma unroll
      for (int ni = 0; ni < 4; ni++) {
        float vv = fminf(fmaxf(acc[ni][r], -CLAMPV), CLAMPV) + fm[ni];
        vals[ni] = vv;
        tm = fmaxf(tm, vv);
      }
#pragma unroll
      for (int d = 1; d < 16; d <<= 1) tm = fmaxf(tm, __shfl_xor(tm, d));
      float mnew = fmaxf(mrow[r], tm);
      float se = 0.f;
#pragma unroll
      for (int ni = 0; ni < 4; ni++) se += __expf(vals[ni] - mnew);
#pragma unroll
      for (int d = 1; d < 16; d <<= 1) se += __shfl_xor(se, d);
      lrow[r] = lrow[r] * __expf(mrow[r] - mnew) + se;
      mrow[r] = mnew;
    }
    __syncthreads();
  }

  float invl[4];
#pragma unroll
  for (int i = 0; i < 4; i++) invl[i] = 1.0f / lrow[i];

  f32x4 apv[4] = {};
  const size_t wbase = (size_t)(bh * TSEQ + tq * 64 + wid * 16 + lhi * 4) * TSEQ;

  // ---------------- sweep 2: weights out + PV ----------------
  for (int s0 = 0; s0 < TSEQ; s0 += 64) {
    gl_lds16(Kh + kg0 + (size_t)s0 * EMB, bufA + tid * 8);
    gl_lds16(Kh + kg1 + (size_t)s0 * EMB, bufA + (tid + 256) * 8);
    gl_lds16(Kl + kg0 + (size_t)s0 * EMB, bufB + tid * 8);
    gl_lds16(Kl + kg1 + (size_t)s0 * EMB, bufB + (tid + 256) * 8);
    gl_lds16(Vt + vg0 + s0, VsH + tid * 8);
    gl_lds16(Vt + vg1 + s0, VsH + (tid + 256) * 8);
    __syncthreads();

    f32x4 acc[4] = {};
#pragma unroll
    for (int ks = 0; ks < 2; ks++) {
#pragma unroll
      for (int ni = 0; ni < 4; ni++) {
        const int br = ni * 16 + l15;
        const int boff = br * 64 + (((ks * 4 + lhi) ^ (br & 7)) * 8);
        short8 bH = *(const short8*)(bufA + boff);
        short8 bL = *(const short8*)(bufB + boff);
        acc[ni] = MFMA(qH[ks], bH, acc[ni]);
        acc[ni] = MFMA(qH[ks], bL, acc[ni]);
        acc[ni] = MFMA(qL[ks], bH, acc[ni]);
      }
    }

    const unsigned long long mb = mbits[b * 32 + (s0 >> 6)];
    float fm[4];
#pragma unroll
    for (int ni = 0; ni < 4; ni++)
      fm[ni] = ((mb >> (ni * 16 + l15)) & 1ull) ? 0.f : NEG_BIG;

#pragma unroll
    for (int r = 0; r < 4; r++) {
      const int rowl = wid * 16 + lhi * 4 + r;
      float* wp = Wout + wbase + (size_t)r * TSEQ + s0;
#pragma unroll
      for (int ni = 0; ni < 4; ni++) {
        const int col = ni * 16 + l15;
        float vv = fminf(fmaxf(acc[ni][r], -CLAMPV), CLAMPV) + fm[ni];
        float w = __expf(vv - mrow[r]) * invl[r];   // masked -> exp(-huge) = 0
        __builtin_nontemporal_store(w, wp + col);
        WsH[rowl * 64 + (((col >> 3) ^ (rowl & 7)) * 8) + (col & 7)] = f2bf(w);
      }
    }

    // PV: Ws rows are wave-private (write->read same wave, lgkmcnt-ordered)
#pragma unroll
    for (int ks = 0; ks < 2; ks++) {
      const int ar = wid * 16 + l15;
      short8 wv = *(const short8*)(WsH + ar * 64 + (((ks * 4 + lhi) ^ (ar & 7)) * 8));
#pragma unroll
      for (int ni = 0; ni < 4; ni++) {
        const int dr = ni * 16 + l15;
        short8 vv = *(const short8*)(VsH + dr * 64 + (((ks * 4 + lhi) ^ (dr & 7)) * 8));
        apv[ni] = MFMA(wv, vv, apv[ni]);
      }
    }
    __syncthreads();
  }

  // ctx epilogue: split hi/lo
#pragma unroll
  for (int ni = 0; ni < 4; ni++)
#pragma unroll
    for (int r = 0; r < 4; r++) {
      const int rowl = wid * 16 + lhi * 4 + r;
      const int d = ni * 16 + l15;
      float c = apv[ni][r];
      ushort hh = f2bf(c);
      const size_t go = (size_t)(q0 + rowl) * EMB + h * HD + d;
      Ch[go] = hh;
      Cl[go] = f2bf(c - bf2f(hh));
    }
}

// ---------------- launch ----------------
extern "C" void kernel_launch(void* const* d_in, const int* in_sizes, int n_in,
                              void* d_out, int out_size, void* d_ws, size_t ws_size,
                              hipStream_t stream) {
  (void)in_sizes; (void)n_in; (void)out_size; (void)ws_size;
  const float* q   = (const float*)d_in[0];
  const float* k   = (const float*)d_in[1];
  const float* v   = (const float*)d_in[2];
  const int*  mask = (const int*)d_in[3];
  const float* Wq  = (const float*)d_in[4];
  const float* bq  = (const float*)d_in[5];
  const float* Wk  = (const float*)d_in[6];
  const float* bk  = (const float*)d_in[7];
  const float* Wv  = (const float*)d_in[8];
  const float* bv  = (const float*)d_in[9];
  const float* Wo  = (const float*)d_in[10];
  const float* bo  = (const float*)d_in[11];

  const size_t TE = (size_t)BSZ * TSEQ * EMB;   // 4M elements
  const size_t WE = (size_t)EMB * EMB;          // 1M elements

  ushort* ws  = (ushort*)d_ws;
  ushort* qbh = ws;        ushort* qbl = qbh + TE;
  ushort* kbh = qbl + TE;  ushort* kbl = kbh + TE;
  ushort* vbh = kbl + TE;  ushort* vbl = vbh + TE;
  ushort* wqh = vbl + TE;  ushort* wql = wqh + WE;
  ushort* wkh = wql + WE;  ushort* wkl = wkh + WE;
  ushort* wvh = wkl + WE;  ushort* wvl = wvh + WE;
  ushort* woh = wvl + WE;  ushort* wol = woh + WE;
  ushort* Qph = wol + WE;  ushort* Qpl = Qph + TE;
  ushort* Kph = Qpl + TE;  ushort* Kpl = Kph + TE;
  ushort* Vth = Kpl + TE;
  unsigned long long* mbits = (unsigned long long*)(Vth + TE);
  // ctx aliases q staging (q consumed by Q-proj before attn runs)
  ushort* Cth = qbh;       ushort* Ctl = qbl;

  mask_bits<<<16, 256, 0, stream>>>(mask, mbits);

  CvtArgs ca;
  ca.src[0] = q;  ca.dh[0] = qbh; ca.dl[0] = qbl; ca.n4[0] = (int)(TE / 4);
  ca.src[1] = k;  ca.dh[1] = kbh; ca.dl[1] = kbl; ca.n4[1] = (int)(TE / 4);
  ca.src[2] = v;  ca.dh[2] = vbh; ca.dl[2] = vbl; ca.n4[2] = (int)(TE / 4);
  ca.src[3] = Wq; ca.dh[3] = wqh; ca.dl[3] = wql; ca.n4[3] = (int)(WE / 4);
  ca.src[4] = Wk; ca.dh[4] = wkh; ca.dl[4] = wkl; ca.n4[4] = (int)(WE / 4);
  ca.src[5] = Wv; ca.dh[5] = wvh; ca.dl[5] = wvl; ca.n4[5] = (int)(WE / 4);
  ca.src[6] = Wo; ca.dh[6] = woh; ca.dl[6] = wol; ca.n4[6] = (int)(WE / 4);
  cvt_all<<<dim3(512, 7), 256, 0, stream>>>(ca);

  dim3 gproj(EMB / 64, (BSZ * TSEQ) / 128);   // (16, 32) = 512 blocks
  gemm_split<0><<<gproj, 256, 0, stream>>>(qbh, qbl, wqh, wql, bq, Qph, Qpl,
                                           BSZ * TSEQ, EMB, EMB, SCALEF);
  gemm_split<0><<<gproj, 256, 0, stream>>>(kbh, kbl, wkh, wkl, bk, Kph, Kpl,
                                           BSZ * TSEQ, EMB, EMB, 1.0f);
  gemm_split<1><<<gproj, 256, 0, stream>>>(vbh, vbl, wvh, wvl, bv, Vth, nullptr,
                                           BSZ * TSEQ, EMB, EMB, 1.0f);

  float* outp = (float*)d_out;
  float* wout = outp + TE;   // outputs concat: out then weights
  attn_kernel<<<dim3(TSEQ / 64, NH, BSZ), 256, 0, stream>>>(
      Qph, Qpl, Kph, Kpl, Vth, mbits, wout, Cth, Ctl);

  gemm_split<2><<<gproj, 256, 0, stream>>>(Cth, Ctl, woh, wol, bo, outp, nullptr,
                                           BSZ * TSEQ, EMB, EMB, 1.0f);
}